// Round 2
// baseline (58.660 us; speedup 1.0000x reference)
//
#include <hip/hip_runtime.h>

#define B_ 2
#define L_ 256
#define H_ 256
#define A_ 32
#define P_ 64

// k1: per 4 rows r = b*L+l: compute h[r, 0..31] then g[r, a, p] = sum_c out_w[p, a*32+c] * h[r, c]
__global__ __launch_bounds__(256) void k1_proj(
    const float* __restrict__ x,     // [B,L,H]
    const float* __restrict__ in_w,  // [A,H]
    const float* __restrict__ in_b,  // [A]
    const float* __restrict__ out_w, // [P, A*A]
    float* __restrict__ g,           // [B*L, A, P]
    float* __restrict__ hg)          // [B*L, A]
{
    __shared__ float xs[4 * H_];     // 4 input rows
    __shared__ float hl[4][A_];
    const int t = threadIdx.x;
    const int r0 = blockIdx.x * 4;

    // stage 4 rows of x (1024 floats = 256 float4)
    {
        const float4* src = (const float4*)(x + (size_t)r0 * H_);
        float4* dst = (float4*)xs;
        dst[t] = src[t];
    }
    __syncthreads();

    // h: 4 rows x 32 outputs, 2 threads per dot of length 256
    {
        const int jj = t >> 6;        // row 0..3 (one wave per row)
        const int rem = t & 63;
        const int a = rem >> 1;       // 0..31
        const int half = rem & 1;
        const float4* w4 = (const float4*)(in_w + a * H_ + half * 128);
        const float4* xv4 = (const float4*)(xs + jj * H_ + half * 128);
        float s = 0.f;
        #pragma unroll
        for (int m = 0; m < 32; ++m) {
            float4 w = w4[m];
            float4 xv = xv4[m];
            s += w.x * xv.x + w.y * xv.y + w.z * xv.z + w.w * xv.w;
        }
        s += __shfl_xor(s, 1);
        if (half == 0) {
            float hv = s + in_b[a];
            hl[jj][a] = hv;
            hg[(r0 + jj) * A_ + a] = hv;
        }
    }
    __syncthreads();

    // g[r, a, p]: thread owns p = t&63, a-range (t>>6)*8 .. +7
    const int p = t & 63;
    const int ag = t >> 6;   // 0..3
    #pragma unroll
    for (int k = 0; k < 8; ++k) {
        const int a = ag * 8 + k;
        const float4* wrow = (const float4*)(out_w + (size_t)p * (A_ * A_) + a * A_);
        float4 w[8];
        #pragma unroll
        for (int m = 0; m < 8; ++m) w[m] = wrow[m];
        #pragma unroll
        for (int jj = 0; jj < 4; ++jj) {
            const float* hh = hl[jj];   // uniform address -> LDS broadcast
            float s = 0.f;
            #pragma unroll
            for (int m = 0; m < 8; ++m) {
                s += w[m].x * hh[4*m]   + w[m].y * hh[4*m+1]
                   + w[m].z * hh[4*m+2] + w[m].w * hh[4*m+3];
            }
            g[((size_t)(r0 + jj) * A_ + a) * P_ + p] = s;   // coalesced over p
        }
    }
}

// k2: tile 16 i x 16 j x 64 p; out[b,i,j,p] = sum_a h[b,i,a]*g[b,j,a,p] + biases + pos
// h is read via BLOCK-UNIFORM addresses -> compiler scalarizes to s_load
// (SGPR operands in the FMAs); no LDS, bounded unroll to avoid spills.
__global__ __launch_bounds__(256) void k2_outer(
    const float* __restrict__ g,      // [B*L, A, P]
    const float* __restrict__ hg,     // [B*L, A]
    const float* __restrict__ out_b,  // [P]
    const float* __restrict__ pos_w,  // [P,17]
    const float* __restrict__ pos_b,  // [P]
    float* __restrict__ out)          // [B, L, L, P]
{
    const int t = threadIdx.x;
    const int i0 = blockIdx.x * 16;
    const int j0 = blockIdx.y * 16;
    const int b = blockIdx.z;

    const int pq = t & 15;            // p-quadrant first -> contiguous wave stores
    const int jl = t >> 4;
    const int p4 = pq * 4;
    const int j = j0 + jl;

    const float4* gp = (const float4*)(g + (size_t)(b * L_ + j) * (A_ * P_) + p4);
    const float* hrow = hg + (size_t)(b * L_ + i0) * A_;   // block-uniform base

    float4 acc[16];
    #pragma unroll
    for (int il = 0; il < 16; ++il) acc[il] = make_float4(0.f, 0.f, 0.f, 0.f);

    #pragma unroll 1
    for (int a0 = 0; a0 < A_; a0 += 4) {
        float4 ga0 = gp[(a0 + 0) * (P_ / 4)];
        float4 ga1 = gp[(a0 + 1) * (P_ / 4)];
        float4 ga2 = gp[(a0 + 2) * (P_ / 4)];
        float4 ga3 = gp[(a0 + 3) * (P_ / 4)];
        #pragma unroll
        for (int il = 0; il < 16; ++il) {
            // uniform address (il, a0 compile/loop constants, no threadIdx) -> s_load
            const float4 h4 = *(const float4*)(hrow + il * A_ + a0);
            acc[il].x += h4.x * ga0.x + h4.y * ga1.x + h4.z * ga2.x + h4.w * ga3.x;
            acc[il].y += h4.x * ga0.y + h4.y * ga1.y + h4.z * ga2.y + h4.w * ga3.y;
            acc[il].z += h4.x * ga0.z + h4.y * ga1.z + h4.z * ga2.z + h4.w * ga3.z;
            acc[il].w += h4.x * ga0.w + h4.y * ga1.w + h4.z * ga2.w + h4.w * ga3.w;
        }
    }

    float4 bias;
    bias.x = out_b[p4 + 0] + pos_b[p4 + 0];
    bias.y = out_b[p4 + 1] + pos_b[p4 + 1];
    bias.z = out_b[p4 + 2] + pos_b[p4 + 2];
    bias.w = out_b[p4 + 3] + pos_b[p4 + 3];

    float4* op = (float4*)(out + (((size_t)(b * L_ + i0)) * L_ + j) * P_ + p4);
    #pragma unroll
    for (int il = 0; il < 16; ++il) {
        int d = (i0 + il) - j;
        d = d < -8 ? -8 : (d > 8 ? 8 : d);
        d += 8;
        float4 v;
        v.x = acc[il].x + bias.x + pos_w[(p4 + 0) * 17 + d];
        v.y = acc[il].y + bias.y + pos_w[(p4 + 1) * 17 + d];
        v.z = acc[il].z + bias.z + pos_w[(p4 + 2) * 17 + d];
        v.w = acc[il].w + bias.w + pos_w[(p4 + 3) * 17 + d];
        op[(size_t)il * (L_ * P_ / 4)] = v;
    }
}

extern "C" void kernel_launch(void* const* d_in, const int* in_sizes, int n_in,
                              void* d_out, int out_size, void* d_ws, size_t ws_size,
                              hipStream_t stream) {
    const float* x     = (const float*)d_in[0];
    const float* in_w  = (const float*)d_in[1];
    const float* in_b  = (const float*)d_in[2];
    const float* out_w = (const float*)d_in[3];
    const float* out_b = (const float*)d_in[4];
    const float* pos_w = (const float*)d_in[5];
    const float* pos_b = (const float*)d_in[6];
    float* out = (float*)d_out;

    float* g  = (float*)d_ws;                                          // 4 MB
    float* hg = (float*)((char*)d_ws + (size_t)B_ * L_ * A_ * P_ * 4); // 64 KB

    k1_proj<<<dim3((B_ * L_) / 4), 256, 0, stream>>>(x, in_w, in_b, out_w, g, hg);
    k2_outer<<<dim3(L_ / 16, L_ / 16, B_), 256, 0, stream>>>(g, hg, out_b, pos_w, pos_b, out);
}

// Round 3
// 33.052 us; speedup vs baseline: 1.7748x; 1.7748x over previous
//
#include <hip/hip_runtime.h>

#define B_ 2
#define L_ 256
#define H_ 256
#define A_ 32
#define P_ 64

typedef __bf16 bf16x8 __attribute__((ext_vector_type(8)));
typedef float  f32x4  __attribute__((ext_vector_type(4)));

// k1: 2 rows per block (256 blocks). Compute h[r,0..31] (f32 in LDS, bf16 to hb),
// then g[r,a,p] = sum_c out_w[p, a*32+c] * h[r,c], stored bf16 TRANSPOSED as gb[r][p][a]
// so k2's MFMA B-fragment (8 consecutive a at fixed p) is one 16B load.
__global__ __launch_bounds__(256) void k1_proj(
    const float* __restrict__ x,     // [B,L,H]
    const float* __restrict__ in_w,  // [A,H]
    const float* __restrict__ in_b,  // [A]
    const float* __restrict__ out_w, // [P, A*A]
    __bf16* __restrict__ gb,         // [B*L][P][A] bf16
    __bf16* __restrict__ hb)         // [B*L][A]   bf16
{
    __shared__ float xs[2 * H_];
    __shared__ float hl[2][A_];
    const int t = threadIdx.x;
    const int r0 = blockIdx.x * 2;

    if (t < 128) ((float4*)xs)[t] = ((const float4*)(x + (size_t)r0 * H_))[t];
    __syncthreads();

    // h: 2 rows x 32 outputs, 4 threads per dot (64 elems each)
    {
        const int jj = t >> 7;        // row 0..1
        const int rem = t & 127;
        const int a = rem >> 2;       // 0..31
        const int q = rem & 3;        // quarter of the 256-dot
        const float4* w4 = (const float4*)(in_w + a * H_ + q * 64);
        const float4* xv4 = (const float4*)(xs + jj * H_ + q * 64);
        float s = 0.f;
        #pragma unroll
        for (int m = 0; m < 16; ++m) {
            float4 w = w4[m], xv = xv4[m];
            s += w.x * xv.x + w.y * xv.y + w.z * xv.z + w.w * xv.w;
        }
        s += __shfl_xor(s, 1);
        s += __shfl_xor(s, 2);
        if (q == 0) {
            float hv = s + in_b[a];
            hl[jj][a] = hv;
            hb[(r0 + jj) * A_ + a] = (__bf16)hv;
        }
    }
    __syncthreads();

    // g: thread owns p = t&63, a-range (t>>6)*8..+7; k INNER-accumulated so the
    // 8 a-values pack into one bf16x8 store per row.
    const int p = t & 63;
    const int ag = t >> 6;   // 0..3
    float sacc[2][8];
    #pragma unroll
    for (int k = 0; k < 8; ++k) {
        const int a = ag * 8 + k;
        const float4* wrow = (const float4*)(out_w + (size_t)p * (A_ * A_) + a * A_);
        float4 w[8];
        #pragma unroll
        for (int m = 0; m < 8; ++m) w[m] = wrow[m];
        #pragma unroll
        for (int jj = 0; jj < 2; ++jj) {
            const float4* hh = (const float4*)hl[jj];   // uniform -> ds_read_b128 broadcast
            float s = 0.f;
            #pragma unroll
            for (int m = 0; m < 8; ++m) {
                float4 h4 = hh[m];
                s += w[m].x * h4.x + w[m].y * h4.y + w[m].z * h4.z + w[m].w * h4.w;
            }
            sacc[jj][k] = s;
        }
    }
    #pragma unroll
    for (int jj = 0; jj < 2; ++jj) {
        bf16x8 v;
        #pragma unroll
        for (int e = 0; e < 8; ++e) v[e] = (__bf16)sacc[jj][e];
        *(bf16x8*)(gb + ((size_t)((r0 + jj) * P_ + p)) * A_ + ag * 8) = v;
    }
}

// k2: out[b,i,j,p] = sum_a h[i,a] g[j,a,p] via mfma_f32_16x16x32_bf16 (K=32=A, no K loop).
// Block = 16 i x 16 j x 64 p. Wave w owns 4 j's; per j: 4 p-group MFMAs (16x16 each).
// D layout (verified): col = lane&15 (=p within group), row = (lane>>4)*4 + reg (=i).
__global__ __launch_bounds__(256) void k2_mfma(
    const __bf16* __restrict__ gb,   // [B*L][P][A]
    const __bf16* __restrict__ hb,   // [B*L][A]
    const float* __restrict__ out_b, // [P]
    const float* __restrict__ pos_w, // [P,17]
    const float* __restrict__ pos_b, // [P]
    float* __restrict__ out)         // [B,L,L,P]
{
    const int t = threadIdx.x;
    const int lane = t & 63;
    const int w = t >> 6;            // wave 0..3
    const int j0 = blockIdx.x * 16;
    const int i0 = blockIdx.y * 16;
    const int b = blockIdx.z;

    const int l15 = lane & 15;
    const int kch = lane >> 4;       // k-chunk 0..3 (same partition for A and B)

    // A-fragment: h rows i0..i0+15; lane: M-row = lane&15, k = kch*8 + e
    const bf16x8 afrag = *(const bf16x8*)(hb + ((size_t)(b * L_ + i0 + l15)) * A_ + kch * 8);

    // per-lane biases for the 4 p-groups (p = pg*16 + l15)
    float bias[4];
    #pragma unroll
    for (int pg = 0; pg < 4; ++pg) {
        const int p = pg * 16 + l15;
        bias[pg] = out_b[p] + pos_b[p];
    }

    const f32x4 zero = {0.f, 0.f, 0.f, 0.f};
    const int irow0 = i0 + (lane >> 4) * 4;   // D-row base for this lane

    #pragma unroll
    for (int tj = 0; tj < 4; ++tj) {
        const int j = j0 + w * 4 + tj;
        const __bf16* gr = gb + ((size_t)(b * L_ + j)) * (P_ * A_);

        bf16x8 bfrag[4];
        #pragma unroll
        for (int pg = 0; pg < 4; ++pg) {
            const int p = pg * 16 + l15;
            bfrag[pg] = *(const bf16x8*)(gr + p * A_ + kch * 8);  // 8 consecutive a
        }

        f32x4 acc[4];
        #pragma unroll
        for (int pg = 0; pg < 4; ++pg)
            acc[pg] = __builtin_amdgcn_mfma_f32_16x16x32_bf16(afrag, bfrag[pg], zero, 0, 0, 0);

        float* orow = out + (((size_t)(b * L_ + irow0)) * L_ + j) * P_;
        #pragma unroll
        for (int pg = 0; pg < 4; ++pg) {
            const int p = pg * 16 + l15;
            #pragma unroll
            for (int r = 0; r < 4; ++r) {
                const int i = irow0 + r;
                int d = i - j;
                d = d < -8 ? -8 : (d > 8 ? 8 : d);
                d += 8;
                orow[(size_t)r * (L_ * P_) + p] = acc[pg][r] + bias[pg] + pos_w[p * 17 + d];
            }
        }
    }
}

extern "C" void kernel_launch(void* const* d_in, const int* in_sizes, int n_in,
                              void* d_out, int out_size, void* d_ws, size_t ws_size,
                              hipStream_t stream) {
    const float* x     = (const float*)d_in[0];
    const float* in_w  = (const float*)d_in[1];
    const float* in_b  = (const float*)d_in[2];
    const float* out_w = (const float*)d_in[3];
    const float* out_b = (const float*)d_in[4];
    const float* pos_w = (const float*)d_in[5];
    const float* pos_b = (const float*)d_in[6];
    float* out = (float*)d_out;

    __bf16* gb = (__bf16*)d_ws;                                   // 2 MB
    __bf16* hb = gb + (size_t)B_ * L_ * P_ * A_;                  // +32 KB

    k1_proj<<<dim3((B_ * L_) / 2), 256, 0, stream>>>(x, in_w, in_b, out_w, gb, hb);
    k2_mfma<<<dim3(L_ / 16, L_ / 16, B_), 256, 0, stream>>>(gb, hb, out_b, pos_w, pos_b, out);
}

// Round 4
// 29.195 us; speedup vs baseline: 2.0092x; 1.1321x over previous
//
#include <hip/hip_runtime.h>

#define B_ 2
#define L_ 256
#define H_ 256
#define A_ 32
#define P_ 64
#define PSTR 76   // posT LDS row stride (floats): 16B-aligned, spreads banks

typedef __bf16 bf16x8 __attribute__((ext_vector_type(8)));
typedef float  f32x4  __attribute__((ext_vector_type(4)));

// k1: 2 rows per block (256 blocks). h[r,0..31] (f32 in LDS, bf16 to hb),
// g[r,a,p] = sum_c out_w[p, a*32+c] * h[r,c], stored bf16 TRANSPOSED as gb[r][p][a].
__global__ __launch_bounds__(256) void k1_proj(
    const float* __restrict__ x,     // [B,L,H]
    const float* __restrict__ in_w,  // [A,H]
    const float* __restrict__ in_b,  // [A]
    const float* __restrict__ out_w, // [P, A*A]
    __bf16* __restrict__ gb,         // [B*L][P][A] bf16
    __bf16* __restrict__ hb)         // [B*L][A]   bf16
{
    __shared__ float xs[2 * H_];
    __shared__ float hl[2][A_];
    const int t = threadIdx.x;
    const int r0 = blockIdx.x * 2;

    if (t < 128) ((float4*)xs)[t] = ((const float4*)(x + (size_t)r0 * H_))[t];
    __syncthreads();

    {
        const int jj = t >> 7;        // row 0..1
        const int rem = t & 127;
        const int a = rem >> 2;       // 0..31
        const int q = rem & 3;
        const float4* w4 = (const float4*)(in_w + a * H_ + q * 64);
        const float4* xv4 = (const float4*)(xs + jj * H_ + q * 64);
        float s = 0.f;
        #pragma unroll
        for (int m = 0; m < 16; ++m) {
            float4 w = w4[m], xv = xv4[m];
            s += w.x * xv.x + w.y * xv.y + w.z * xv.z + w.w * xv.w;
        }
        s += __shfl_xor(s, 1);
        s += __shfl_xor(s, 2);
        if (q == 0) {
            float hv = s + in_b[a];
            hl[jj][a] = hv;
            hb[(r0 + jj) * A_ + a] = (__bf16)hv;
        }
    }
    __syncthreads();

    const int p = t & 63;
    const int ag = t >> 6;   // 0..3
    float sacc[2][8];
    #pragma unroll
    for (int k = 0; k < 8; ++k) {
        const int a = ag * 8 + k;
        const float4* wrow = (const float4*)(out_w + (size_t)p * (A_ * A_) + a * A_);
        float4 w[8];
        #pragma unroll
        for (int m = 0; m < 8; ++m) w[m] = wrow[m];
        #pragma unroll
        for (int jj = 0; jj < 2; ++jj) {
            const float4* hh = (const float4*)hl[jj];   // uniform -> broadcast
            float s = 0.f;
            #pragma unroll
            for (int m = 0; m < 8; ++m) {
                float4 h4 = hh[m];
                s += w[m].x * h4.x + w[m].y * h4.y + w[m].z * h4.z + w[m].w * h4.w;
            }
            sacc[jj][k] = s;
        }
    }
    #pragma unroll
    for (int jj = 0; jj < 2; ++jj) {
        bf16x8 v;
        #pragma unroll
        for (int e = 0; e < 8; ++e) v[e] = (__bf16)sacc[jj][e];
        *(bf16x8*)(gb + ((size_t)((r0 + jj) * P_ + p)) * A_ + ag * 8) = v;
    }
}

// k2: out[b,i,j,p] = sum_a g[j,a,p] h[i,a] via mfma(A=g, B=h): D[m=p][n=i].
// Lane: i = i0 + (lane&15); p = pg*16 + (lane>>4)*4 + reg -> float4 stores over p.
// Tile 16i x 8j per block, wave owns 2 j. posT LDS table folds pos_w+pos_b+out_b.
__global__ __launch_bounds__(256) void k2_mfma(
    const __bf16* __restrict__ gb,   // [B*L][P][A]
    const __bf16* __restrict__ hb,   // [B*L][A]
    const float* __restrict__ out_b, // [P]
    const float* __restrict__ pos_w, // [P,17]
    const float* __restrict__ pos_b, // [P]
    float* __restrict__ out)         // [B,L,L,P]
{
    __shared__ float posT[17 * PSTR];
    const int t = threadIdx.x;

    for (int e = t; e < 17 * P_; e += 256) {
        const int d = e >> 6, p = e & 63;
        posT[d * PSTR + p] = pos_w[p * 17 + d] + pos_b[p] + out_b[p];
    }
    __syncthreads();

    const int lane = t & 63;
    const int w = t >> 6;            // wave 0..3
    const int j0 = blockIdx.x * 8;
    const int i0 = blockIdx.y * 16;
    const int b = blockIdx.z;

    const int l15 = lane & 15;
    const int hi = lane >> 4;        // 0..3
    const int i = i0 + l15;
    const int p_r0 = hi * 4;         // p offset within p-group

    // B-fragment (h): n = i = lane&15-row, k = hi*8 + e
    const bf16x8 hfrag = *(const bf16x8*)(hb + ((size_t)(b * L_ + i)) * A_ + hi * 8);

    const f32x4 zero = {0.f, 0.f, 0.f, 0.f};

    #pragma unroll
    for (int tj = 0; tj < 2; ++tj) {
        const int j = j0 + w * 2 + tj;
        const __bf16* gr = gb + ((size_t)(b * L_ + j)) * (P_ * A_);

        bf16x8 gfrag[4];
        #pragma unroll
        for (int pg = 0; pg < 4; ++pg)
            gfrag[pg] = *(const bf16x8*)(gr + (pg * 16 + l15) * A_ + hi * 8);

        f32x4 acc[4];
        #pragma unroll
        for (int pg = 0; pg < 4; ++pg)
            acc[pg] = __builtin_amdgcn_mfma_f32_16x16x32_bf16(gfrag[pg], hfrag, zero, 0, 0, 0);

        int d = i - j;
        d = d < -8 ? -8 : (d > 8 ? 8 : d);
        d += 8;

        float* op = out + (((size_t)(b * L_ + i)) * L_ + j) * P_;
        #pragma unroll
        for (int pg = 0; pg < 4; ++pg) {
            const f32x4 pe = *(const f32x4*)(posT + d * PSTR + pg * 16 + p_r0);
            __builtin_nontemporal_store(acc[pg] + pe, (f32x4*)(op + pg * 16 + p_r0));
        }
    }
}

extern "C" void kernel_launch(void* const* d_in, const int* in_sizes, int n_in,
                              void* d_out, int out_size, void* d_ws, size_t ws_size,
                              hipStream_t stream) {
    const float* x     = (const float*)d_in[0];
    const float* in_w  = (const float*)d_in[1];
    const float* in_b  = (const float*)d_in[2];
    const float* out_w = (const float*)d_in[3];
    const float* out_b = (const float*)d_in[4];
    const float* pos_w = (const float*)d_in[5];
    const float* pos_b = (const float*)d_in[6];
    float* out = (float*)d_out;

    __bf16* gb = (__bf16*)d_ws;                                   // 2 MB
    __bf16* hb = gb + (size_t)B_ * L_ * P_ * A_;                  // +32 KB

    k1_proj<<<dim3((B_ * L_) / 2), 256, 0, stream>>>(x, in_w, in_b, out_w, gb, hb);
    k2_mfma<<<dim3(L_ / 8, L_ / 16, B_), 256, 0, stream>>>(gb, hb, out_b, pos_w, pos_b, out);
}